// Round 1
// baseline (646.646 us; speedup 1.0000x reference)
//
#include <hip/hip_runtime.h>
#include <hip/hip_bf16.h>

#define DM   1024
#define DI   64
#define H_   16
#define B_   2
#define S_   2048
#define NTOK 4096   // B*S

typedef unsigned short u16;
typedef __attribute__((ext_vector_type(8))) short s16x8;
typedef __attribute__((ext_vector_type(4))) float f32x4;
typedef __attribute__((ext_vector_type(4))) unsigned int u32x4;
typedef __attribute__((ext_vector_type(4))) unsigned short u16x4;

static __device__ __forceinline__ u16 f2bf(float f) {
  unsigned int u = __builtin_bit_cast(unsigned int, f);
  unsigned int r = (u + 0x7fffu + ((u >> 16) & 1u)) >> 16;
  return (u16)r;
}

// ---------------- small prep kernels ----------------

__global__ void k_cvt_x(const float* __restrict__ in, u16* __restrict__ out) {
  int i = (blockIdx.x * 256 + threadIdx.x) * 4;
  float4 v = *(const float4*)&in[i];
  u16x4 o;
  o[0] = f2bf(v.x); o[1] = f2bf(v.y); o[2] = f2bf(v.z); o[3] = f2bf(v.w);
  *(u16x4*)&out[i] = o;
}

__global__ void k_small(const float* __restrict__ bq, const float* __restrict__ bk,
                        const float* __restrict__ bv, const int* __restrict__ mask,
                        float* __restrict__ bc, float* __restrict__ mbias) {
  int t = blockIdx.x * 256 + threadIdx.x;
  if (t < 1024) bc[t] = bq[t];
  else if (t < 2048) bc[t] = bk[t - 1024];
  else if (t < 4096) bc[t] = bv[t - 2048];
  else if (t < 8192) { int i = t - 4096; mbias[i] = mask[i] ? 0.f : -1e30f; }
}

// transpose [R][C] f32 -> [C][R] bf16, one matrix per blockIdx.z
__global__ void k_tr_f2b(const float* __restrict__ in, u16* __restrict__ out, int R, int C) {
  __shared__ float t[32][33];
  const float* src = in + (size_t)blockIdx.z * R * C;
  u16* dst = out + (size_t)blockIdx.z * C * R;
  int r0 = blockIdx.y * 32, c0 = blockIdx.x * 32;
  for (int i = threadIdx.y; i < 32; i += 8)
    t[i][threadIdx.x] = src[(size_t)(r0 + i) * C + c0 + threadIdx.x];
  __syncthreads();
  for (int i = threadIdx.y; i < 32; i += 8)
    dst[(size_t)(c0 + i) * R + r0 + threadIdx.x] = f2bf(t[threadIdx.x][i]);
}

// transpose [R][C] bf16 -> [C][R] bf16, one matrix per blockIdx.z
__global__ void k_tr_b2b(const u16* __restrict__ in, u16* __restrict__ out, int R, int C) {
  __shared__ u16 t[32][33];
  const u16* src = in + (size_t)blockIdx.z * R * C;
  u16* dst = out + (size_t)blockIdx.z * C * R;
  int r0 = blockIdx.y * 32, c0 = blockIdx.x * 32;
  for (int i = threadIdx.y; i < 32; i += 8)
    t[i][threadIdx.x] = src[(size_t)(r0 + i) * C + c0 + threadIdx.x];
  __syncthreads();
  for (int i = threadIdx.y; i < 32; i += 8)
    dst[(size_t)(c0 + i) * R + r0 + threadIdx.x] = t[threadIdx.x][i];
}

// ---------------- GEMM: C[m][n] = sum_k A[m][k]*Bt[n][k] (+bias) ----------------
// MODE 0: QKV projection epilogue (scatter to Q/K/V bf16)
// MODE 1: output projection epilogue (f32 to res)
template<int MODE>
__global__ __launch_bounds__(256)
void k_gemm(const u16* __restrict__ A, const u16* __restrict__ Bt,
            const float* __restrict__ bias, int Kdim,
            u16* __restrict__ q_out, u16* __restrict__ k_out, u16* __restrict__ v_out,
            float* __restrict__ res_out) {
  const int tid = threadIdx.x;
  const int l = tid & 63, w = tid >> 6;
  const int wm = w >> 1, wn = w & 1;
  const int g = l >> 4, lo = l & 15;
  const int m0 = blockIdx.y * 128, n0 = blockIdx.x * 128;
  __shared__ u16 As[128 * 72];
  __shared__ u16 Bs[128 * 72];
  f32x4 acc[4][4] = {};
  for (int kt = 0; kt < Kdim; kt += 64) {
    __syncthreads();
    for (int cid = tid; cid < 1024; cid += 256) {
      int r = cid >> 3, c = (cid & 7) * 8;
      *(u32x4*)&As[r * 72 + c] = *(const u32x4*)&A[(size_t)(m0 + r) * Kdim + kt + c];
      *(u32x4*)&Bs[r * 72 + c] = *(const u32x4*)&Bt[(size_t)(n0 + r) * Kdim + kt + c];
    }
    __syncthreads();
    for (int kc = 0; kc < 64; kc += 32) {
      s16x8 a[4], b[4];
      for (int i = 0; i < 4; i++)
        a[i] = *(const s16x8*)&As[(wm * 64 + i * 16 + lo) * 72 + kc + 8 * g];
      for (int i = 0; i < 4; i++)
        b[i] = *(const s16x8*)&Bs[(wn * 64 + i * 16 + lo) * 72 + kc + 8 * g];
      for (int mi = 0; mi < 4; mi++)
        for (int ni = 0; ni < 4; ni++)
          acc[mi][ni] = __builtin_amdgcn_mfma_f32_16x16x32_bf16(a[mi], b[ni], acc[mi][ni], 0, 0, 0);
    }
  }
  for (int mi = 0; mi < 4; mi++)
    for (int ni = 0; ni < 4; ni++)
      for (int j = 0; j < 4; j++) {
        int m = m0 + wm * 64 + mi * 16 + g * 4 + j;
        int n = n0 + wn * 64 + ni * 16 + lo;
        float v = acc[mi][ni][j] + bias[n];
        if (MODE == 0) {
          int bb = m >> 11, s = m & 2047;
          if (n < 1024) {
            int h = n >> 6, d = n & 63;
            q_out[(((size_t)h * B_ + bb) * S_ + s) * 64 + d] = f2bf(v);
          } else if (n < 2048) {
            int nn = n - 1024; int h = nn >> 6, d = nn & 63;
            k_out[(((size_t)h * B_ + bb) * S_ + s) * 64 + d] = f2bf(v);
          } else {
            int nn = n - 2048; int h = nn >> 7, d = nn & 127;
            v_out[(((size_t)h * B_ + bb) * S_ + s) * 128 + d] = f2bf(v);
          }
        } else {
          res_out[(size_t)m * 1024 + n] = v;
        }
      }
}

// ---------------- fused attention ----------------
// grid: (S/64 row blocks, H*B). block: 256 (4 waves), wave w owns rows [w*16, w*16+16)
__global__ __launch_bounds__(256)
void k_attn(const u16* __restrict__ Qb, const u16* __restrict__ Kb,
            const u16* __restrict__ Vtb, const float* __restrict__ mbias,
            const float* __restrict__ lam_p, const float* __restrict__ ln_g,
            const float* __restrict__ ln_b, float* __restrict__ A_out,
            u16* __restrict__ cat) {
  const int tid = threadIdx.x, l = tid & 63, w = tid >> 6;
  const int g = l >> 4, lo = l & 15;
  const int hb = blockIdx.y, b = hb & 1, h = hb >> 1;
  const int s0 = blockIdx.x * 64;
  const float pfac = 1.0f - lam_p[0];
  const float scale = 0.03125f;  // 1/sqrt(1024)

  __shared__ u16 Qs[64 * 72];
  __shared__ u16 Ks[64 * 72];
  __shared__ u16 Vs[128 * 72];
  __shared__ u16 Ps[4][16 * 72];

  const u16* Qhb = Qb + (size_t)hb * S_ * 64;
  const u16* Khb = Kb + (size_t)hb * S_ * 64;
  const u16* Vthb = Vtb + (size_t)hb * 128 * S_;
  const float* mb = mbias + (size_t)b * S_;

  for (int cid = tid; cid < 512; cid += 256) {
    int r = cid >> 3, c = (cid & 7) * 8;
    *(u32x4*)&Qs[r * 72 + c] = *(const u32x4*)&Qhb[(size_t)(s0 + r) * 64 + c];
  }

  float m_run[4] = {-INFINITY, -INFINITY, -INFINITY, -INFINITY};
  float ssum[4] = {0.f, 0.f, 0.f, 0.f};

  // pass 1: stats
  for (int kt = 0; kt < S_; kt += 64) {
    __syncthreads();
    for (int cid = tid; cid < 512; cid += 256) {
      int r = cid >> 3, c = (cid & 7) * 8;
      *(u32x4*)&Ks[r * 72 + c] = *(const u32x4*)&Khb[(size_t)(kt + r) * 64 + c];
    }
    __syncthreads();
    s16x8 a0 = *(const s16x8*)&Qs[(w * 16 + lo) * 72 + 8 * g];
    s16x8 a1 = *(const s16x8*)&Qs[(w * 16 + lo) * 72 + 32 + 8 * g];
    float sv[4][4];
    for (int nf = 0; nf < 4; nf++) {
      s16x8 b0 = *(const s16x8*)&Ks[(nf * 16 + lo) * 72 + 8 * g];
      s16x8 b1 = *(const s16x8*)&Ks[(nf * 16 + lo) * 72 + 32 + 8 * g];
      f32x4 z = {};
      z = __builtin_amdgcn_mfma_f32_16x16x32_bf16(a0, b0, z, 0, 0, 0);
      z = __builtin_amdgcn_mfma_f32_16x16x32_bf16(a1, b1, z, 0, 0, 0);
      float mbv = mb[kt + nf * 16 + lo];
      for (int j = 0; j < 4; j++) sv[nf][j] = z[j] * scale + mbv;
    }
    for (int j = 0; j < 4; j++) {
      float tm = fmaxf(fmaxf(sv[0][j], sv[1][j]), fmaxf(sv[2][j], sv[3][j]));
      for (int msk = 1; msk < 16; msk <<= 1) tm = fmaxf(tm, __shfl_xor(tm, msk, 64));
      float nm = fmaxf(m_run[j], tm);
      float ps = 0.f;
      for (int nf = 0; nf < 4; nf++) ps += __expf(sv[nf][j] - nm);
      for (int msk = 1; msk < 16; msk <<= 1) ps += __shfl_xor(ps, msk, 64);
      ssum[j] = ssum[j] * __expf(m_run[j] - nm) + ps;
      m_run[j] = nm;
    }
  }
  float rinv[4];
  for (int j = 0; j < 4; j++) rinv[j] = pfac / ssum[j];

  // pass 2: recompute, write A, accumulate O = A*V
  f32x4 o[8] = {};
  for (int kt = 0; kt < S_; kt += 64) {
    __syncthreads();
    for (int cid = tid; cid < 512; cid += 256) {
      int r = cid >> 3, c = (cid & 7) * 8;
      *(u32x4*)&Ks[r * 72 + c] = *(const u32x4*)&Khb[(size_t)(kt + r) * 64 + c];
    }
    for (int cid = tid; cid < 1024; cid += 256) {
      int r = cid >> 3, c = (cid & 7) * 8;
      *(u32x4*)&Vs[r * 72 + c] = *(const u32x4*)&Vthb[(size_t)r * S_ + kt + c];
    }
    __syncthreads();
    s16x8 a0 = *(const s16x8*)&Qs[(w * 16 + lo) * 72 + 8 * g];
    s16x8 a1 = *(const s16x8*)&Qs[(w * 16 + lo) * 72 + 32 + 8 * g];
    for (int nf = 0; nf < 4; nf++) {
      s16x8 b0 = *(const s16x8*)&Ks[(nf * 16 + lo) * 72 + 8 * g];
      s16x8 b1 = *(const s16x8*)&Ks[(nf * 16 + lo) * 72 + 32 + 8 * g];
      f32x4 z = {};
      z = __builtin_amdgcn_mfma_f32_16x16x32_bf16(a0, b0, z, 0, 0, 0);
      z = __builtin_amdgcn_mfma_f32_16x16x32_bf16(a1, b1, z, 0, 0, 0);
      float mbv = mb[kt + nf * 16 + lo];
      float* Ar = A_out + ((size_t)hb * S_ + (s0 + w * 16 + g * 4)) * S_ + kt + nf * 16 + lo;
      for (int j = 0; j < 4; j++) {
        float p = __expf((z[j] * scale + mbv) - m_run[j]) * rinv[j];
        Ar[(size_t)j * S_] = p;
        Ps[w][(g * 4 + j) * 72 + nf * 16 + lo] = f2bf(p);
      }
    }
    for (int kc = 0; kc < 2; kc++) {
      s16x8 pa = *(const s16x8*)&Ps[w][lo * 72 + kc * 32 + 8 * g];
      for (int vf = 0; vf < 8; vf++) {
        s16x8 bv = *(const s16x8*)&Vs[(vf * 16 + lo) * 72 + kc * 32 + 8 * g];
        o[vf] = __builtin_amdgcn_mfma_f32_16x16x32_bf16(pa, bv, o[vf], 0, 0, 0);
      }
    }
  }

  // LayerNorm(128) * 0.2 epilogue -> cat[b][s][h*128 + c]
  for (int j = 0; j < 4; j++) {
    float sum = 0.f, sq = 0.f;
    for (int vf = 0; vf < 8; vf++) { float xv = o[vf][j]; sum += xv; sq += xv * xv; }
    for (int msk = 1; msk < 16; msk <<= 1) {
      sum += __shfl_xor(sum, msk, 64);
      sq += __shfl_xor(sq, msk, 64);
    }
    float mean = sum * (1.f / 128.f);
    float var = sq * (1.f / 128.f) - mean * mean;
    float rstd = rsqrtf(var + 1e-5f);
    int s = s0 + w * 16 + g * 4 + j;
    u16* cp = cat + ((size_t)(b * S_ + s)) * 2048 + h * 128;
    for (int vf = 0; vf < 8; vf++) {
      int c = vf * 16 + lo;
      float y = (o[vf][j] - mean) * rstd * ln_g[c] + ln_b[c];
      cp[c] = f2bf(y * 0.2f);
    }
  }
}

// ---------------- launcher ----------------

extern "C" void kernel_launch(void* const* d_in, const int* in_sizes, int n_in,
                              void* d_out, int out_size, void* d_ws, size_t ws_size,
                              hipStream_t stream) {
  const float* x    = (const float*)d_in[0];
  const float* lam  = (const float*)d_in[1];
  const int*   mask = (const int*)d_in[2];
  const float* wq   = (const float*)d_in[3];
  const float* bq   = (const float*)d_in[4];
  const float* wk   = (const float*)d_in[5];
  const float* bk   = (const float*)d_in[6];
  const float* wv   = (const float*)d_in[7];
  const float* bv   = (const float*)d_in[8];
  const float* wo   = (const float*)d_in[9];
  const float* bo   = (const float*)d_in[10];
  const float* lng  = (const float*)d_in[11];
  const float* lnb  = (const float*)d_in[12];

  float* res = (float*)d_out;
  float* A   = res + (size_t)NTOK * DM;

  char* ws = (char*)d_ws;
  size_t off = 0;
  auto alloc = [&](size_t bytes) {
    void* p = ws + off;
    off += (bytes + 255) & ~(size_t)255;
    return p;
  };
  u16*   xb    = (u16*)  alloc((size_t)NTOK * DM * 2);       // 8 MB (dead after gemm1)
  u16*   Wct   = (u16*)  alloc((size_t)4096 * 1024 * 2);     // 8 MB (dead after gemm1)
  float* bc    = (float*)alloc(4096 * 4);
  float* mbias = (float*)alloc(4096 * 4);
  u16*   wot   = (u16*)  alloc((size_t)1024 * 2048 * 2);
  u16*   Qb    = (u16*)  alloc((size_t)32 * S_ * 64 * 2);
  u16*   Kb2   = (u16*)  alloc((size_t)32 * S_ * 64 * 2);
  u16*   Vb    = (u16*)  alloc((size_t)32 * S_ * 128 * 2);
  u16*   Vtb   = (u16*)  alloc((size_t)32 * S_ * 128 * 2);
  u16*   catb  = (u16*)ws;  // reuse xb+Wct region (exactly 16 MB), both dead by k_attn

  k_cvt_x<<<4096, 256, 0, stream>>>(x, xb);
  k_small<<<32, 256, 0, stream>>>(bq, bk, bv, mask, bc, mbias);
  k_tr_f2b<<<dim3(2, 32, 16), dim3(32, 8), 0, stream>>>(wq, Wct, 1024, 64);
  k_tr_f2b<<<dim3(2, 32, 16), dim3(32, 8), 0, stream>>>(wk, Wct + 1024 * 1024, 1024, 64);
  k_tr_f2b<<<dim3(4, 32, 16), dim3(32, 8), 0, stream>>>(wv, Wct + 2048 * 1024, 1024, 128);
  k_tr_f2b<<<dim3(32, 64, 1), dim3(32, 8), 0, stream>>>(wo, wot, 2048, 1024);
  k_gemm<0><<<dim3(32, 32), 256, 0, stream>>>(xb, Wct, bc, 1024, Qb, Kb2, Vb, nullptr);
  k_tr_b2b<<<dim3(4, 64, 32), dim3(32, 8), 0, stream>>>(Vb, Vtb, 2048, 128);
  k_attn<<<dim3(32, 32), 256, 0, stream>>>(Qb, Kb2, Vtb, mbias, lam, lng, lnb, A, catb);
  k_gemm<1><<<dim3(8, 32), 256, 0, stream>>>(catb, wot, bo, 2048, nullptr, nullptr, nullptr, res);
}